// Round 8
// baseline (197.394 us; speedup 1.0000x reference)
//
#include <hip/hip_runtime.h>

#define NB 4
#define CIN 64
#define COUT 64
#define H 128
#define W 128
#define H2 256
#define W2 256
#define HSX 23            // halo row stride (f32x2 units), 22 used
#define HROWS 38          // 32 + 6
#define CST 14            // coarse row stride (f32x2), 13 used
#define CROWS 21
#define ZS 40             // zbuf row stride (ushorts) = 80B

// ws layout (float units)
#define WS_W    0         // bf16 weights ushort[32][64][32] = 32768 floats
#define WS_P1   32768     // per-tile partial sums  [4*64][128]
#define WS_P2   65536     // per-tile partial sumsq [4*64][128]
#define WS_MU   98304
#define WS_RSTD 98560

// ---------------------------------------------------------------------------
// Compile-time DISCO basis (replicates the numpy double-precision computation)
// ---------------------------------------------------------------------------
constexpr double csqrt(double x) {
    double g = x > 1.0 ? x : 1.0;
    for (int i = 0; i < 64; ++i) g = 0.5 * (g + x / g);
    return g;
}
constexpr double catan_pos(double x) {
    double f = 1.0;
    for (int i = 0; i < 6; ++i) { x = x / (1.0 + csqrt(1.0 + x * x)); f *= 2.0; }
    double x2 = x * x, s = 0.0, term = x;
    for (int n = 0; n < 10; ++n) { s += term / (2 * n + 1) * ((n & 1) ? -1.0 : 1.0); term *= x2; }
    return f * s;
}
constexpr double catan2c(double y, double x) {
    const double PI = 3.141592653589793;
    if (x == 0.0 && y == 0.0) return 0.0;
    double ax = x < 0 ? -x : x, ay = y < 0 ? -y : y;
    double a = (ax >= ay) ? catan_pos(ay / ax) : (PI / 2.0 - catan_pos(ax / ay));
    if (x < 0) a = PI - a;
    return (y < 0) ? -a : a;
}

struct PsiTab { double v[81][9]; };
constexpr PsiTab compute_psi() {
    PsiTab P{};
    const double hy = 1.0 / 256.0;
    const double rcut = 0.015;
    const double dr = 0.0075;
    const double PI = 3.141592653589793;
    const double TWO_PI = 6.283185307179586;
    const double dphi = PI / 2.0;
    for (int ky = 0; ky < 9; ++ky)
        for (int kx = 0; kx < 9; ++kx) {
            double dy = (double)(ky - 4) * hy;
            double dx = (double)(kx - 4) * hy;
            double r = csqrt(dy * dy + dx * dx);
            double phi = catan2c(dy, dx);
            if (phi < 0.0) phi += TWO_PI;
            for (int k = 0; k < 9; ++k) {
                int ir = (k == 0) ? 0 : ((k - 1) / 4 + 1);
                double ctr = ir * dr;
                double ad = r > ctr ? r - ctr : ctr - r;
                double rv = (ad <= dr && r <= rcut) ? 1.0 - ad / dr : 0.0;
                double val;
                if (k == 0) val = rv;
                else {
                    int ip = (k - 1) % 4;
                    double da = phi - ip * dphi; if (da < 0) da = -da;
                    double d2 = TWO_PI - da; if (d2 < da) da = d2;
                    double pv = (da <= dphi) ? 1.0 - da / dphi : 0.0;
                    val = rv * pv;
                }
                P.v[ky * 9 + kx][k] = val * (hy * hy);
            }
        }
    return P;
}

// [ky][kx][k] tables + per-(dm,dx) any-use flag for the 2-pixel shared loop
struct Psi3 {
    float val[9][9][9];
    bool  nz[9][9][9];
    bool  tapany[8][7];   // [dm+3][dx+3], dm in -3..4, dx in -3..3
};
constexpr Psi3 make_psi3() {
    Psi3 S{};
    PsiTab P = compute_psi();
    for (int ky = 0; ky < 9; ++ky)
        for (int kx = 0; kx < 9; ++kx)
            for (int k = 0; k < 9; ++k) {
                S.val[ky][kx][k] = (float)P.v[ky * 9 + kx][k];
                S.nz[ky][kx][k]  = (P.v[ky * 9 + kx][k] != 0.0);
            }
    for (int dm = -3; dm <= 4; ++dm)
        for (int dx = -3; dx <= 3; ++dx) {
            bool a = false;
            if (dm <= 3)  for (int k = 0; k < 9; ++k) a = a || S.nz[dm + 4][dx + 4][k];
            if (dm >= -2) for (int k = 0; k < 9; ++k) a = a || S.nz[dm + 3][dx + 4][k];
            S.tapany[dm + 3][dx + 3] = a;
        }
    return S;
}
constexpr Psi3 PS3 = make_psi3();

using f32x2  = __attribute__((ext_vector_type(2))) float;
using f32x4  = __attribute__((ext_vector_type(4))) float;
using bf16x8 = __attribute__((ext_vector_type(8))) short;

__device__ __forceinline__ unsigned short f2bf_rne(float f) {
    unsigned u = __float_as_uint(f);
    unsigned r = (u + 0x7fff + ((u >> 16) & 1)) >> 16;
    return (unsigned short)r;
}
// RTZ pack of two floats to one u32 of 2 bf16 (bias cancels in InstanceNorm)
__device__ __forceinline__ unsigned pkrtz(float a, float b) {
    return (__float_as_uint(a) >> 16) | (__float_as_uint(b) & 0xffff0000u);
}

// ---------------------------------------------------------------------------
// Setup: pre-transpose weights to bf16 wsW[g][o][32]  (kk = ch*16 + k, pads 0)
// ---------------------------------------------------------------------------
__global__ void setup_w(const float* __restrict__ wgt, float* __restrict__ ws) {
    unsigned short* wsW = (unsigned short*)(ws + WS_W);
    const int g = blockIdx.x;          // channel pair 0..31
    const int t = threadIdx.x;         // 256
    const int o = t >> 2;
    const int k0 = (t & 3) * 8;
#pragma unroll
    for (int j = 0; j < 8; ++j) {
        int kk = k0 + j;
        int ch = kk >> 4, k = kk & 15;
        float v = (k < 9) ? wgt[((size_t)o * CIN + 2 * g + ch) * 9 + k] : 0.f;
        wsW[g * 2048 + o * 32 + kk] = f2bf_rne(v);
    }
}

// ---------------------------------------------------------------------------
// Fused upsample + DISCO conv. Block = 32x16 px tile (512 px), 4 waves.
// Thread owns 2 VERTICALLY adjacent px -> tap rows shared: 52 b64 reads per
// 2px instead of 90. Coarse 21x13 patch (ch-paired f32x2) -> fine halo via
// pk-lerp -> z via compile-time nz-pruned taps (v_pk_fma_f32) -> RTZ bf16 ->
// MFMA 16x16x32 over K = 2ch x 16 (pads zero). 2 barriers/pair.
// ---------------------------------------------------------------------------
__global__ __launch_bounds__(256, 2) void conv_kernel(const float* __restrict__ img,
                                                      float* __restrict__ out,
                                                      float* __restrict__ ws) {
    __shared__ __align__(16) unsigned short zbuf[512][ZS]; // [px][kk] bf16
    __shared__ f32x2 halo[2][HROWS * HSX];                 // [buf] {ch0,ch1} f32
    __shared__ f32x2 coarse[2][CROWS * CST];
    __shared__ float red1[4][64], red2[4][64];

    const int tid  = threadIdx.x;
    const int bid  = blockIdx.x;
    const int n    = bid >> 7;
    const int tile = bid & 127;
    const int ty0  = (tile >> 4) << 5;     // 8 tile-rows of 32
    const int tx0  = (tile & 15) << 4;     // 16 tile-cols of 16

    const int ry = tid >> 4, c = tid & 15;
    const int hbase = (2 * ry + 3) * HSX + (c + 3);
    const int px0 = 32 * ry + c;           // fine px (2ry, c); pair is px0+16
    const int wv  = tid >> 6;
    const int l   = tid & 63;
    const int a16 = l & 15;
    const int kseg = (l >> 4) * 8;

    const unsigned short* wsW = (const unsigned short*)(ws + WS_W);

    // zero zbuf once (kk pads stay zero forever)
    {
        uint4* zr = (uint4*)&zbuf[0][0];
#pragma unroll
        for (int j = 0; j < 10; ++j) zr[tid + j * 256] = make_uint4(0, 0, 0, 0);
    }

    const float cs = 0.49803922f;   // 127/255

    // ---- block-constant coarse patch base ----
    int cy0 = (int)floorf((float)(ty0 - 3) * cs); cy0 = min(max(cy0, 0), 128 - CROWS);
    int cx0 = (int)floorf((float)(tx0 - 3) * cs); cx0 = min(max(cx0, 0), 128 - 13);

    // ---- coarse loader (273 elems, 2 slots) ----
    int cgoff[2];
    float cv0[2], cv1[2];
#pragma unroll
    for (int j = 0; j < 2; ++j) {
        int e = tid + j * 256;
        if (e < CROWS * 13) {
            int ci = e / 13, cj = e - ci * 13;
            cgoff[j] = (cy0 + ci) * W + (cx0 + cj);
        }
    }
    auto cload = [&](int g) {
        const float* b = img + ((size_t)n * CIN + 2 * g) * (H * W);
#pragma unroll
        for (int j = 0; j < 2; ++j)
            if (tid < CROWS * 13 - j * 256) {
                cv0[j] = b[cgoff[j]];
                cv1[j] = b[cgoff[j] + H * W];
            }
    };
    auto cwrite = [&](int q) {
#pragma unroll
        for (int j = 0; j < 2; ++j)
            if (tid < CROWS * 13 - j * 256) {
                int e = tid + j * 256;
                int ci = e / 13, cj = e - ci * 13;
                coarse[q][ci * CST + cj] = (f32x2){cv0[j], cv1[j]};
            }
    };

    // ---- fine-halo metadata: 836 elems, 4 slots, packed u32 + fy + fx ----
    unsigned fM[4];
    float fFY[4], fFX[4];
#pragma unroll
    for (int j = 0; j < 4; ++j) {
        int e = tid + j * 256;
        if (e < HROWS * 22) {
            int hy = e / 22, hx = e - hy * 22;
            int uy = ty0 - 3 + hy, ux = tx0 - 3 + hx;
            unsigned zf = (((unsigned)uy >= 256u) || ((unsigned)ux >= 256u)) ? 1u : 0u;
            float syf = (float)uy * cs;
            float sxf = (float)ux * cs;
            int y0 = (int)floorf(syf);
            int x0 = (int)floorf(sxf);
            fFY[j] = syf - (float)y0;
            fFX[j] = sxf - (float)x0;
            int y0c = min(max(y0, 0), 127), x0c = min(max(x0, 0), 127);
            int dyo = (min(y0c + 1, 127) - y0c);           // 0/1
            int dxo = (min(x0c + 1, 127) - x0c);           // 0/1
            unsigned A = (unsigned)((y0c - cy0) * CST + (x0c - cx0));
            fM[j] = A | ((unsigned)dxo << 9) | ((unsigned)dyo << 10) | (zf << 11)
                      | ((unsigned)(hy * HSX + hx) << 12);
        }
    }

    auto fine_build = [&](int q) {
#pragma unroll
        for (int j = 0; j < 4; ++j)
            if (tid < HROWS * 22 - j * 256) {
                unsigned m = fM[j];
                const f32x2* cb = &coarse[q][0];
                int A = m & 511;
                int dxo = (m >> 9) & 1;
                int dyo = ((m >> 10) & 1) * CST;
                f32x2 c00 = cb[A],       c01 = cb[A + dxo];
                f32x2 c10 = cb[A + dyo], c11 = cb[A + dyo + dxo];
                f32x2 fyv = (f32x2){fFY[j], fFY[j]};
                f32x2 fxv = (f32x2){fFX[j], fFX[j]};
                f32x2 t0 = c00 + fyv * (c10 - c00);
                f32x2 t1 = c01 + fyv * (c11 - c01);
                f32x2 v  = t0 + fxv * (t1 - t0);
                if (m & (1u << 11)) v = (f32x2){0.f, 0.f};
                halo[q][m >> 12] = v;
            }
    };

    // z for BOTH pixels of this thread (rows 2ry, 2ry+1), both channels
    auto zphase = [&](int q) {
        const f32x2* hb = &halo[q][hbase - 72];   // all imm offsets >= 0
        f32x2 z0[9], z1[9];
#pragma unroll
        for (int k = 0; k < 9; ++k) { z0[k] = (f32x2){0.f, 0.f}; z1[k] = (f32x2){0.f, 0.f}; }
#pragma unroll
        for (int dm = -3; dm <= 4; ++dm) {
#pragma unroll
            for (int dx = -3; dx <= 3; ++dx) {
                if (PS3.tapany[dm + 3][dx + 3]) {
                    f32x2 h = hb[72 + dm * HSX + dx];
#pragma unroll
                    for (int k = 0; k < 9; ++k) {
                        if (dm <= 3 && PS3.nz[dm + 4][dx + 4][k])
                            z0[k] += h * PS3.val[dm + 4][dx + 4][k];
                        if (dm >= -2 && PS3.nz[dm + 3][dx + 4][k])
                            z1[k] += h * PS3.val[dm + 3][dx + 4][k];
                    }
                }
            }
        }
        unsigned short* zr0 = &zbuf[px0][0];
        *(uint4*)zr0 = make_uint4(pkrtz(z0[0].x, z0[1].x), pkrtz(z0[2].x, z0[3].x),
                                  pkrtz(z0[4].x, z0[5].x), pkrtz(z0[6].x, z0[7].x));
        zr0[8] = (unsigned short)(__float_as_uint(z0[8].x) >> 16);
        *(uint4*)(zr0 + 16) = make_uint4(pkrtz(z0[0].y, z0[1].y), pkrtz(z0[2].y, z0[3].y),
                                         pkrtz(z0[4].y, z0[5].y), pkrtz(z0[6].y, z0[7].y));
        zr0[24] = (unsigned short)(__float_as_uint(z0[8].y) >> 16);
        unsigned short* zr1 = &zbuf[px0 + 16][0];
        *(uint4*)zr1 = make_uint4(pkrtz(z1[0].x, z1[1].x), pkrtz(z1[2].x, z1[3].x),
                                  pkrtz(z1[4].x, z1[5].x), pkrtz(z1[6].x, z1[7].x));
        zr1[8] = (unsigned short)(__float_as_uint(z1[8].x) >> 16);
        *(uint4*)(zr1 + 16) = make_uint4(pkrtz(z1[0].y, z1[1].y), pkrtz(z1[2].y, z1[3].y),
                                         pkrtz(z1[4].y, z1[5].y), pkrtz(z1[6].y, z1[7].y));
        zr1[24] = (unsigned short)(__float_as_uint(z1[8].y) >> 16);
    };

    f32x4 acc[4][8];
#pragma unroll
    for (int m = 0; m < 4; ++m)
#pragma unroll
        for (int t = 0; t < 8; ++t) acc[m][t] = (f32x4){0.f, 0.f, 0.f, 0.f};

    // ---- prologue ----
    cload(0);
    cwrite(0);
    __syncthreads();
    fine_build(0);
    cload(1);
    __syncthreads();

#pragma unroll 1
    for (int g = 0; g < 32; ++g) {
        const int p = g & 1;
        zphase(p);                       // halo[p] -> zbuf
        if (g < 31) cwrite(p ^ 1);       // regs(g+1) -> coarse[p^1]
        bf16x8 af[4];
        {
            const unsigned short* wp = wsW + g * 2048 + a16 * 32 + kseg;
#pragma unroll
            for (int m = 0; m < 4; ++m)
                af[m] = *(const bf16x8*)(wp + m * 512);
        }
        __syncthreads();                 // B1: zbuf + coarse[p^1] ready

        union { uint4 q4; bf16x8 v; } bfr;
#pragma unroll
        for (int t = 0; t < 8; ++t) {
            bfr.q4 = *(const uint4*)&zbuf[wv * 128 + t * 16 + a16][kseg];
#pragma unroll
            for (int m = 0; m < 4; ++m)
                acc[m][t] = __builtin_amdgcn_mfma_f32_16x16x32_bf16(af[m], bfr.v, acc[m][t], 0, 0, 0);
        }

        if (g < 31) fine_build(p ^ 1);   // halo[p^1] <- coarse[p^1] (overlaps MFMA)
        if (g < 30) cload(g + 2);        // global -> regs for pair g+2
        __syncthreads();                 // B2
    }

    // ---- epilogue: instance-norm partials + store y ----
#pragma unroll
    for (int m = 0; m < 4; ++m) {
#pragma unroll
        for (int r4 = 0; r4 < 4; ++r4) {
            float s = 0.f, q = 0.f;
#pragma unroll
            for (int t = 0; t < 8; ++t) {
                float v = acc[m][t][r4];
                s += v; q = fmaf(v, v, q);
            }
#pragma unroll
            for (int msk = 1; msk < 16; msk <<= 1) {
                s += __shfl_xor(s, msk);
                q += __shfl_xor(q, msk);
            }
            if (a16 == 0) {
                int o = m * 16 + (l >> 4) * 4 + r4;
                red1[wv][o] = s;
                red2[wv][o] = q;
            }
        }
    }

    const size_t nbase = (size_t)n * COUT * (H2 * W2);
#pragma unroll
    for (int m = 0; m < 4; ++m)
#pragma unroll
        for (int t = 0; t < 8; ++t) {
            int Y = ty0 + wv * 8 + t;
            int X = tx0 + a16;
#pragma unroll
            for (int r4 = 0; r4 < 4; ++r4) {
                int o = m * 16 + (l >> 4) * 4 + r4;
                out[nbase + (size_t)o * (H2 * W2) + Y * W2 + X] = acc[m][t][r4];
            }
        }
    __syncthreads();
    if (tid < 64) {
        float S1 = red1[0][tid] + red1[1][tid] + red1[2][tid] + red1[3][tid];
        float S2 = red2[0][tid] + red2[1][tid] + red2[2][tid] + red2[3][tid];
        ws[WS_P1 + (n * COUT + tid) * 128 + tile] = S1;
        ws[WS_P2 + (n * COUT + tid) * 128 + tile] = S2;
    }
}

// ---------------------------------------------------------------------------
// Stats: reduce 128 tile-partials per (n,c)
// ---------------------------------------------------------------------------
__global__ void stats_kernel(float* __restrict__ ws) {
    const int co = blockIdx.x;
    const int t  = threadIdx.x;   // 64
    float s1 = ws[WS_P1 + co * 128 + t] + ws[WS_P1 + co * 128 + t + 64];
    float s2 = ws[WS_P2 + co * 128 + t] + ws[WS_P2 + co * 128 + t + 64];
#pragma unroll
    for (int m = 1; m < 64; m <<= 1) { s1 += __shfl_xor(s1, m); s2 += __shfl_xor(s2, m); }
    if (t == 0) {
        const float inv = 1.f / 65536.f;
        float mu  = s1 * inv;
        float var = s2 * inv - mu * mu;
        ws[WS_MU + co]   = mu;
        ws[WS_RSTD + co] = 1.f / sqrtf(var + 1e-5f);
    }
}

// ---------------------------------------------------------------------------
// Normalize + LeakyReLU(0.2), in place on d_out
// ---------------------------------------------------------------------------
__global__ void norm_kernel(float* __restrict__ out, const float* __restrict__ ws) {
    const int total = NB * COUT * H2 * W2 / 4;
    for (int idx = blockIdx.x * blockDim.x + threadIdx.x; idx < total;
         idx += gridDim.x * blockDim.x) {
        int co = idx >> 14;
        float mu = ws[WS_MU + co];
        float rs = ws[WS_RSTD + co];
        float4 v = ((float4*)out)[idx];
        float* p = (float*)&v;
#pragma unroll
        for (int j = 0; j < 4; ++j) {
            float t = (p[j] - mu) * rs;
            p[j] = (t >= 0.f) ? t : 0.2f * t;
        }
        ((float4*)out)[idx] = v;
    }
}

extern "C" void kernel_launch(void* const* d_in, const int* in_sizes, int n_in,
                              void* d_out, int out_size, void* d_ws, size_t ws_size,
                              hipStream_t stream) {
    const float* img = (const float*)d_in[0];
    const float* wgt = (const float*)d_in[1];
    float* out = (float*)d_out;
    float* ws  = (float*)d_ws;

    setup_w<<<32, 256, 0, stream>>>(wgt, ws);
    conv_kernel<<<NB * 128, 256, 0, stream>>>(img, out, ws);
    stats_kernel<<<256, 64, 0, stream>>>(ws);
    norm_kernel<<<2048, 256, 0, stream>>>(out, ws);
}

// Round 9
// 155.466 us; speedup vs baseline: 1.2697x; 1.2697x over previous
//
#include <hip/hip_runtime.h>

#define NB 4
#define CIN 64
#define COUT 64
#define H 128
#define W 128
#define H2 256
#define W2 256
#define HSX 23            // halo row stride (f32x2 units)
#define ZS 40             // zbuf row stride (ushorts) = 80B, rows 16B-aligned

// ws layout (float units)
#define WS_W    0         // bf16 weights ushort[32][64][32] = 32768 floats
#define WS_P1   32768     // per-tile partial sums  [4*64][256]
#define WS_P2   98304     // per-tile partial sumsq [4*64][256]
#define WS_MU   163840
#define WS_RSTD 164096

// ---------------------------------------------------------------------------
// Compile-time DISCO basis (replicates the numpy double-precision computation)
// ---------------------------------------------------------------------------
constexpr double csqrt(double x) {
    double g = x > 1.0 ? x : 1.0;
    for (int i = 0; i < 64; ++i) g = 0.5 * (g + x / g);
    return g;
}
constexpr double catan_pos(double x) {
    double f = 1.0;
    for (int i = 0; i < 6; ++i) { x = x / (1.0 + csqrt(1.0 + x * x)); f *= 2.0; }
    double x2 = x * x, s = 0.0, term = x;
    for (int n = 0; n < 10; ++n) { s += term / (2 * n + 1) * ((n & 1) ? -1.0 : 1.0); term *= x2; }
    return f * s;
}
constexpr double catan2c(double y, double x) {
    const double PI = 3.141592653589793;
    if (x == 0.0 && y == 0.0) return 0.0;
    double ax = x < 0 ? -x : x, ay = y < 0 ? -y : y;
    double a = (ax >= ay) ? catan_pos(ay / ax) : (PI / 2.0 - catan_pos(ax / ay));
    if (x < 0) a = PI - a;
    return (y < 0) ? -a : a;
}

struct PsiTab { double v[81][9]; };
constexpr PsiTab compute_psi() {
    PsiTab P{};
    const double hy = 1.0 / 256.0;
    const double rcut = 0.015;
    const double dr = 0.0075;
    const double PI = 3.141592653589793;
    const double TWO_PI = 6.283185307179586;
    const double dphi = PI / 2.0;
    for (int ky = 0; ky < 9; ++ky)
        for (int kx = 0; kx < 9; ++kx) {
            double dy = (double)(ky - 4) * hy;
            double dx = (double)(kx - 4) * hy;
            double r = csqrt(dy * dy + dx * dx);
            double phi = catan2c(dy, dx);
            if (phi < 0.0) phi += TWO_PI;
            for (int k = 0; k < 9; ++k) {
                int ir = (k == 0) ? 0 : ((k - 1) / 4 + 1);
                double ctr = ir * dr;
                double ad = r > ctr ? r - ctr : ctr - r;
                double rv = (ad <= dr && r <= rcut) ? 1.0 - ad / dr : 0.0;
                double val;
                if (k == 0) val = rv;
                else {
                    int ip = (k - 1) % 4;
                    double da = phi - ip * dphi; if (da < 0) da = -da;
                    double d2 = TWO_PI - da; if (d2 < da) da = d2;
                    double pv = (da <= dphi) ? 1.0 - da / dphi : 0.0;
                    val = rv * pv;
                }
                P.v[ky * 9 + kx][k] = val * (hy * hy);
            }
        }
    return P;
}

struct TapTab {
    int nt;
    int off[48];          // dy*HSX + dx (f32x2 offset from thread base)
    float val[48][9];
    bool nz[48][9];
};
constexpr TapTab make_taps() {
    TapTab T{};
    PsiTab P = compute_psi();
    for (int ky = 0; ky < 9; ++ky)
        for (int kx = 0; kx < 9; ++kx) {
            int t = ky * 9 + kx;
            bool any = false;
            for (int k = 0; k < 9; ++k) if (P.v[t][k] != 0.0) any = true;
            if (!any) continue;
            int dy = ky - 4, dx = kx - 4;    // support guarantees |dy|,|dx| <= 3
            T.off[T.nt] = dy * HSX + dx;
            for (int k = 0; k < 9; ++k) {
                T.val[T.nt][k] = (float)P.v[t][k];
                T.nz[T.nt][k] = (P.v[t][k] != 0.0);
            }
            T.nt++;
        }
    return T;
}
constexpr TapTab TT = make_taps();
constexpr int NT = TT.nt;
static_assert(NT > 0 && NT <= 48, "tap table overflow");

using f32x2  = __attribute__((ext_vector_type(2))) float;
using f32x4  = __attribute__((ext_vector_type(4))) float;
using bf16x8 = __attribute__((ext_vector_type(8))) short;

__device__ __forceinline__ unsigned short f2bf_rne(float f) {
    unsigned u = __float_as_uint(f);
    unsigned r = (u + 0x7fff + ((u >> 16) & 1)) >> 16;
    return (unsigned short)r;
}
// RTZ pack of two floats to one u32 of 2 bf16 (bias cancels in InstanceNorm)
__device__ __forceinline__ unsigned pkrtz(float a, float b) {
    return (__float_as_uint(a) >> 16) | (__float_as_uint(b) & 0xffff0000u);
}

// ---------------------------------------------------------------------------
// Setup: pre-transpose weights to bf16 wsW[g][o][32]  (kk = ch*16 + k, pads 0)
// ---------------------------------------------------------------------------
__global__ void setup_w(const float* __restrict__ wgt, float* __restrict__ ws) {
    unsigned short* wsW = (unsigned short*)(ws + WS_W);
    const int g = blockIdx.x;          // channel pair 0..31
    const int t = threadIdx.x;         // 256
    const int o = t >> 2;
    const int k0 = (t & 3) * 8;
#pragma unroll
    for (int j = 0; j < 8; ++j) {
        int kk = k0 + j;
        int ch = kk >> 4, k = kk & 15;
        float v = (k < 9) ? wgt[((size_t)o * CIN + 2 * g + ch) * 9 + k] : 0.f;
        wsW[g * 2048 + o * 32 + kk] = f2bf_rne(v);
    }
}

// ---------------------------------------------------------------------------
// Fused upsample + DISCO conv. Block = 16x16 px tile (256 px), 4 waves.
// 5-stage 1-barrier pipeline: cload(j)@j-3 -> cwrite(j)@j-2 -> fine_build(j)
// @j-1 -> zphase(j)@j -> MFMA(j)@j+1. coarse/halo/zbuf parity-double-buffered;
// all phases in an iteration touch disjoint buffers -> ONE barrier per iter.
// ---------------------------------------------------------------------------
__global__ __launch_bounds__(256, 2) void conv_kernel(const float* __restrict__ img,
                                                      float* __restrict__ out,
                                                      float* __restrict__ ws) {
    __shared__ __align__(16) unsigned short zbuf[2][256][ZS]; // [buf][px][kk]
    __shared__ f32x2 halo[2][22 * HSX];        // [buf] {ch0,ch1} f32
    __shared__ f32x2 coarse[2][14 * 15];       // [buf] {ch0,ch1} f32
    __shared__ float red1[4][64], red2[4][64];

    const int tid  = threadIdx.x;
    const int bid  = blockIdx.x;
    const int n    = bid >> 8;
    const int tile = bid & 255;
    const int ty0  = (tile >> 4) << 4;
    const int tx0  = (tile & 15) << 4;

    const int r = tid >> 4, c = tid & 15;
    const int hbase = (r + 3) * HSX + (c + 3);
    const int wv  = tid >> 6;
    const int l   = tid & 63;
    const int a16 = l & 15;
    const int kseg = (l >> 4) * 8;

    const unsigned short* wsW = (const unsigned short*)(ws + WS_W);

    // zero both zbuf buffers once (kk pads stay zero forever)
    {
        uint4* zr = (uint4*)&zbuf[0][0][0];
#pragma unroll
        for (int j = 0; j < 10; ++j) zr[tid + j * 256] = make_uint4(0, 0, 0, 0);
    }

    const float cs = 0.49803922f;   // 127/255

    // ---- block-constant coarse patch base ----
    int cy0 = (int)floorf((float)(ty0 - 3) * cs); cy0 = min(max(cy0, 0), 114);
    int cx0 = (int)floorf((float)(tx0 - 3) * cs); cx0 = min(max(cx0, 0), 114);

    // ---- coarse loader invariants (1 elem/thread, 196 used) ----
    const bool cok = tid < 196;
    const int ci = tid / 14, cj = tid - ci * 14;
    const int cgoff = (cy0 + ci) * W + (cx0 + cj);
    const int cwidx = ci * 15 + cj;
    float cv0 = 0.f, cv1 = 0.f;

    auto cload = [&](int g) {
        if (cok) {
            const float* b = img + ((size_t)n * CIN + 2 * g) * (H * W) + cgoff;
            cv0 = b[0];
            cv1 = b[H * W];
        }
    };
    auto cwrite = [&](int q) {
        if (cok) coarse[q][cwidx] = (f32x2){cv0, cv1};
    };

    // ---- fine-halo metadata: 484 elems, 2 slots, packed u32 + fy + fx ----
    unsigned fM[2];
    float fFY[2], fFX[2];
#pragma unroll
    for (int j = 0; j < 2; ++j) {
        int e = tid + j * 256;
        if (e < 484) {
            int hy = e / 22, hx = e - hy * 22;
            int uy = ty0 - 3 + hy, ux = tx0 - 3 + hx;
            unsigned zf = (((unsigned)uy >= 256u) || ((unsigned)ux >= 256u)) ? 1u : 0u;
            float syf = (float)uy * cs;
            float sxf = (float)ux * cs;
            int y0 = (int)floorf(syf);
            int x0 = (int)floorf(sxf);
            fFY[j] = syf - (float)y0;
            fFX[j] = sxf - (float)x0;
            int y0c = min(max(y0, 0), 127), x0c = min(max(x0, 0), 127);
            int dyo = min(y0c + 1, 127) - y0c;            // 0/1
            int dxo = min(x0c + 1, 127) - x0c;            // 0/1
            unsigned A = (unsigned)((y0c - cy0) * 15 + (x0c - cx0));
            fM[j] = A | ((unsigned)dxo << 9) | ((unsigned)dyo << 10) | (zf << 11)
                      | ((unsigned)(hy * HSX + hx) << 12);
        }
    }

    auto fine_build = [&](int q) {
#pragma unroll
        for (int j = 0; j < 2; ++j)
            if (tid < 484 - j * 256) {
                unsigned m = fM[j];
                const f32x2* cb = &coarse[q][0];
                int A = m & 511;
                int dxo = (m >> 9) & 1;
                int dyo = ((m >> 10) & 1) * 15;
                f32x2 c00 = cb[A],       c01 = cb[A + dxo];
                f32x2 c10 = cb[A + dyo], c11 = cb[A + dyo + dxo];
                f32x2 fyv = (f32x2){fFY[j], fFY[j]};
                f32x2 fxv = (f32x2){fFX[j], fFX[j]};
                f32x2 t0 = c00 + fyv * (c10 - c00);
                f32x2 t1 = c01 + fyv * (c11 - c01);
                f32x2 v  = t0 + fxv * (t1 - t0);
                if (m & (1u << 11)) v = (f32x2){0.f, 0.f};
                halo[q][m >> 12] = v;
            }
    };

    auto zphase = [&](int p) {
        const f32x2* hb = &halo[p][hbase - 72];   // all imm offsets >= 0
        f32x2 z[9];
#pragma unroll
        for (int k = 0; k < 9; ++k) z[k] = (f32x2){0.f, 0.f};
#pragma unroll
        for (int t = 0; t < NT; ++t) {
            f32x2 h = hb[72 + TT.off[t]];
#pragma unroll
            for (int k = 0; k < 9; ++k)
                if (TT.nz[t][k]) z[k] += h * TT.val[t][k];   // v_pk_fma_f32
        }
        unsigned short* zr = &zbuf[p][tid][0];
        *(uint4*)zr = make_uint4(pkrtz(z[0].x, z[1].x), pkrtz(z[2].x, z[3].x),
                                 pkrtz(z[4].x, z[5].x), pkrtz(z[6].x, z[7].x));
        zr[8] = (unsigned short)(__float_as_uint(z[8].x) >> 16);
        *(uint4*)(zr + 16) = make_uint4(pkrtz(z[0].y, z[1].y), pkrtz(z[2].y, z[3].y),
                                        pkrtz(z[4].y, z[5].y), pkrtz(z[6].y, z[7].y));
        zr[24] = (unsigned short)(__float_as_uint(z[8].y) >> 16);
    };

    f32x4 acc[4][4];
#pragma unroll
    for (int m = 0; m < 4; ++m)
#pragma unroll
        for (int t = 0; t < 4; ++t) acc[m][t] = (f32x4){0.f, 0.f, 0.f, 0.f};

    // ---- prologue: coarse[0]=pair0, halo[0]=pair0, coarse[1]=pair1, regs=pair2
    cload(0); cwrite(0);
    __syncthreads();
    fine_build(0);        // coarse[0] -> halo[0]
    cload(1);
    __syncthreads();
    cwrite(1);            // regs(pair1) -> coarse[1]
    cload(2);
    __syncthreads();

#pragma unroll 1
    for (int i = 0; i <= 32; ++i) {
        // matrix pipe first: MFMA for pair i-1 (zbuf[(i-1)&1], weights i-1)
        if (i >= 1) {
            const int zp = (i - 1) & 1;
            bf16x8 af[4];
            const unsigned short* wp = wsW + (i - 1) * 2048 + a16 * 32 + kseg;
#pragma unroll
            for (int m = 0; m < 4; ++m)
                af[m] = *(const bf16x8*)(wp + m * 512);
            union { uint4 q4; bf16x8 v; } bfr;
#pragma unroll
            for (int t = 0; t < 4; ++t) {
                bfr.q4 = *(const uint4*)&zbuf[zp][wv * 64 + t * 16 + a16][kseg];
#pragma unroll
                for (int m = 0; m < 4; ++m)
                    acc[m][t] = __builtin_amdgcn_mfma_f32_16x16x32_bf16(af[m], bfr.v, acc[m][t], 0, 0, 0);
            }
        }
        if (i < 32)  zphase(i & 1);          // halo[i&1] -> zbuf[i&1]   (pair i)
        if (i <= 29) cwrite(i & 1);          // regs(pair i+2) -> coarse[i&1]
        if (i <= 30) fine_build((i + 1) & 1);// coarse[(i+1)&1] -> halo[(i+1)&1]
        if (i <= 28) cload(i + 3);           // global -> regs (pair i+3)
        __syncthreads();
    }

    // ---- epilogue: instance-norm partials + store y ----
#pragma unroll
    for (int m = 0; m < 4; ++m) {
#pragma unroll
        for (int r4 = 0; r4 < 4; ++r4) {
            float s = 0.f, q = 0.f;
#pragma unroll
            for (int t = 0; t < 4; ++t) {
                float v = acc[m][t][r4];
                s += v; q = fmaf(v, v, q);
            }
#pragma unroll
            for (int msk = 1; msk < 16; msk <<= 1) {
                s += __shfl_xor(s, msk);
                q += __shfl_xor(q, msk);
            }
            if (a16 == 0) {
                int o = m * 16 + (l >> 4) * 4 + r4;
                red1[wv][o] = s;
                red2[wv][o] = q;
            }
        }
    }

    const size_t nbase = (size_t)n * COUT * (H2 * W2);
#pragma unroll
    for (int m = 0; m < 4; ++m)
#pragma unroll
        for (int t = 0; t < 4; ++t) {
            int Y = ty0 + wv * 4 + t;
            int X = tx0 + a16;
#pragma unroll
            for (int r4 = 0; r4 < 4; ++r4) {
                int o = m * 16 + (l >> 4) * 4 + r4;
                out[nbase + (size_t)o * (H2 * W2) + Y * W2 + X] = acc[m][t][r4];
            }
        }
    __syncthreads();
    if (tid < 64) {
        float S1 = red1[0][tid] + red1[1][tid] + red1[2][tid] + red1[3][tid];
        float S2 = red2[0][tid] + red2[1][tid] + red2[2][tid] + red2[3][tid];
        ws[WS_P1 + (n * COUT + tid) * 256 + tile] = S1;
        ws[WS_P2 + (n * COUT + tid) * 256 + tile] = S2;
    }
}

// ---------------------------------------------------------------------------
// Stats: reduce 256 tile-partials per (n,c)
// ---------------------------------------------------------------------------
__global__ void stats_kernel(float* __restrict__ ws) {
    const int co  = blockIdx.x;
    const int tid = threadIdx.x;   // 256
    float s1 = ws[WS_P1 + co * 256 + tid];
    float s2 = ws[WS_P2 + co * 256 + tid];
#pragma unroll
    for (int m = 1; m < 64; m <<= 1) { s1 += __shfl_xor(s1, m); s2 += __shfl_xor(s2, m); }
    __shared__ float r1[4], r2[4];
    if ((tid & 63) == 0) { r1[tid >> 6] = s1; r2[tid >> 6] = s2; }
    __syncthreads();
    if (tid == 0) {
        float S1 = r1[0] + r1[1] + r1[2] + r1[3];
        float S2 = r2[0] + r2[1] + r2[2] + r2[3];
        const float inv = 1.f / 65536.f;
        float mu  = S1 * inv;
        float var = S2 * inv - mu * mu;
        ws[WS_MU + co]   = mu;
        ws[WS_RSTD + co] = 1.f / sqrtf(var + 1e-5f);
    }
}

// ---------------------------------------------------------------------------
// Normalize + LeakyReLU(0.2), in place on d_out
// ---------------------------------------------------------------------------
__global__ void norm_kernel(float* __restrict__ out, const float* __restrict__ ws) {
    const int total = NB * COUT * H2 * W2 / 4;
    for (int idx = blockIdx.x * blockDim.x + threadIdx.x; idx < total;
         idx += gridDim.x * blockDim.x) {
        int co = idx >> 14;
        float mu = ws[WS_MU + co];
        float rs = ws[WS_RSTD + co];
        float4 v = ((float4*)out)[idx];
        float* p = (float*)&v;
#pragma unroll
        for (int j = 0; j < 4; ++j) {
            float t = (p[j] - mu) * rs;
            p[j] = (t >= 0.f) ? t : 0.2f * t;
        }
        ((float4*)out)[idx] = v;
    }
}

extern "C" void kernel_launch(void* const* d_in, const int* in_sizes, int n_in,
                              void* d_out, int out_size, void* d_ws, size_t ws_size,
                              hipStream_t stream) {
    const float* img = (const float*)d_in[0];
    const float* wgt = (const float*)d_in[1];
    float* out = (float*)d_out;
    float* ws  = (float*)d_ws;

    setup_w<<<32, 256, 0, stream>>>(wgt, ws);
    conv_kernel<<<NB * 256, 256, 0, stream>>>(img, out, ws);
    stats_kernel<<<256, 256, 0, stream>>>(ws);
    norm_kernel<<<2048, 256, 0, stream>>>(out, ws);
}

// Round 10
// 153.404 us; speedup vs baseline: 1.2868x; 1.0134x over previous
//
#include <hip/hip_runtime.h>

#define NB 4
#define CIN 64
#define COUT 64
#define H 128
#define W 128
#define H2 256
#define W2 256
#define HSX 23            // halo row stride (f32x2 units)
#define ZS 36             // zbuf row stride (ushorts) = 72B -> 50.4KB LDS, 3 blk/CU

// ws layout (float units)
#define WS_W    0         // bf16 weights ushort[32][64][32] = 32768 floats
#define WS_P1   32768     // per-tile partial sums  [4*64][256]
#define WS_P2   98304     // per-tile partial sumsq [4*64][256]
#define WS_MU   163840
#define WS_RSTD 164096

// ---------------------------------------------------------------------------
// Compile-time DISCO basis (replicates the numpy double-precision computation)
// ---------------------------------------------------------------------------
constexpr double csqrt(double x) {
    double g = x > 1.0 ? x : 1.0;
    for (int i = 0; i < 64; ++i) g = 0.5 * (g + x / g);
    return g;
}
constexpr double catan_pos(double x) {
    double f = 1.0;
    for (int i = 0; i < 6; ++i) { x = x / (1.0 + csqrt(1.0 + x * x)); f *= 2.0; }
    double x2 = x * x, s = 0.0, term = x;
    for (int n = 0; n < 10; ++n) { s += term / (2 * n + 1) * ((n & 1) ? -1.0 : 1.0); term *= x2; }
    return f * s;
}
constexpr double catan2c(double y, double x) {
    const double PI = 3.141592653589793;
    if (x == 0.0 && y == 0.0) return 0.0;
    double ax = x < 0 ? -x : x, ay = y < 0 ? -y : y;
    double a = (ax >= ay) ? catan_pos(ay / ax) : (PI / 2.0 - catan_pos(ax / ay));
    if (x < 0) a = PI - a;
    return (y < 0) ? -a : a;
}

struct PsiTab { double v[81][9]; };
constexpr PsiTab compute_psi() {
    PsiTab P{};
    const double hy = 1.0 / 256.0;
    const double rcut = 0.015;
    const double dr = 0.0075;
    const double PI = 3.141592653589793;
    const double TWO_PI = 6.283185307179586;
    const double dphi = PI / 2.0;
    for (int ky = 0; ky < 9; ++ky)
        for (int kx = 0; kx < 9; ++kx) {
            double dy = (double)(ky - 4) * hy;
            double dx = (double)(kx - 4) * hy;
            double r = csqrt(dy * dy + dx * dx);
            double phi = catan2c(dy, dx);
            if (phi < 0.0) phi += TWO_PI;
            for (int k = 0; k < 9; ++k) {
                int ir = (k == 0) ? 0 : ((k - 1) / 4 + 1);
                double ctr = ir * dr;
                double ad = r > ctr ? r - ctr : ctr - r;
                double rv = (ad <= dr && r <= rcut) ? 1.0 - ad / dr : 0.0;
                double val;
                if (k == 0) val = rv;
                else {
                    int ip = (k - 1) % 4;
                    double da = phi - ip * dphi; if (da < 0) da = -da;
                    double d2 = TWO_PI - da; if (d2 < da) da = d2;
                    double pv = (da <= dphi) ? 1.0 - da / dphi : 0.0;
                    val = rv * pv;
                }
                P.v[ky * 9 + kx][k] = val * (hy * hy);
            }
        }
    return P;
}

struct TapTab {
    int nt;
    int off[48];          // dy*HSX + dx (f32x2 offset from thread base)
    float val[48][9];
    bool nz[48][9];
};
constexpr TapTab make_taps() {
    TapTab T{};
    PsiTab P = compute_psi();
    for (int ky = 0; ky < 9; ++ky)
        for (int kx = 0; kx < 9; ++kx) {
            int t = ky * 9 + kx;
            bool any = false;
            for (int k = 0; k < 9; ++k) if (P.v[t][k] != 0.0) any = true;
            if (!any) continue;
            int dy = ky - 4, dx = kx - 4;    // support guarantees |dy|,|dx| <= 3
            T.off[T.nt] = dy * HSX + dx;
            for (int k = 0; k < 9; ++k) {
                T.val[T.nt][k] = (float)P.v[t][k];
                T.nz[T.nt][k] = (P.v[t][k] != 0.0);
            }
            T.nt++;
        }
    return T;
}
constexpr TapTab TT = make_taps();
constexpr int NT = TT.nt;
static_assert(NT > 0 && NT <= 48, "tap table overflow");

using f32x2  = __attribute__((ext_vector_type(2))) float;
using f32x4  = __attribute__((ext_vector_type(4))) float;
using bf16x8 = __attribute__((ext_vector_type(8))) short;

__device__ __forceinline__ unsigned short f2bf_rne(float f) {
    unsigned u = __float_as_uint(f);
    unsigned r = (u + 0x7fff + ((u >> 16) & 1)) >> 16;
    return (unsigned short)r;
}
// RTZ pack of two floats to one u32 of 2 bf16 (bias cancels in InstanceNorm)
__device__ __forceinline__ unsigned pkrtz(float a, float b) {
    return (__float_as_uint(a) >> 16) | (__float_as_uint(b) & 0xffff0000u);
}

// ---------------------------------------------------------------------------
// Setup: pre-transpose weights to bf16 wsW[g][o][32]  (kk = ch*16 + k, pads 0)
// ---------------------------------------------------------------------------
__global__ void setup_w(const float* __restrict__ wgt, float* __restrict__ ws) {
    unsigned short* wsW = (unsigned short*)(ws + WS_W);
    const int g = blockIdx.x;          // channel pair 0..31
    const int t = threadIdx.x;         // 256
    const int o = t >> 2;
    const int k0 = (t & 3) * 8;
#pragma unroll
    for (int j = 0; j < 8; ++j) {
        int kk = k0 + j;
        int ch = kk >> 4, k = kk & 15;
        float v = (k < 9) ? wgt[((size_t)o * CIN + 2 * g + ch) * 9 + k] : 0.f;
        wsW[g * 2048 + o * 32 + kk] = f2bf_rne(v);
    }
}

// ---------------------------------------------------------------------------
// Fused upsample + DISCO conv. Block = 16x16 px tile (256 px), 4 waves.
// 5-stage 1-barrier pipeline: cload(j)@j-3 -> cwrite(j)@j-2 -> fine_build(j)
// @j-1 -> zphase(j)@j -> MFMA(j)@j+1. coarse/halo/zbuf parity-double-buffered.
// ZS=36 (72B rows, b64 ops): LDS 50.4KB -> 3 blocks/CU (12 waves/CU).
// ---------------------------------------------------------------------------
__global__ __launch_bounds__(256, 2) void conv_kernel(const float* __restrict__ img,
                                                      float* __restrict__ out,
                                                      float* __restrict__ ws) {
    __shared__ __align__(16) unsigned short zbuf[2][256][ZS]; // [buf][px][kk]
    __shared__ f32x2 halo[2][22 * HSX];        // [buf] {ch0,ch1} f32
    __shared__ f32x2 coarse[2][14 * 15];       // [buf] {ch0,ch1} f32
    __shared__ float red1[4][64], red2[4][64];

    const int tid  = threadIdx.x;
    const int bid  = blockIdx.x;
    const int n    = bid >> 8;
    const int tile = bid & 255;
    const int ty0  = (tile >> 4) << 4;
    const int tx0  = (tile & 15) << 4;

    const int r = tid >> 4, c = tid & 15;
    const int hbase = (r + 3) * HSX + (c + 3);
    const int wv  = tid >> 6;
    const int l   = tid & 63;
    const int a16 = l & 15;
    const int kseg = (l >> 4) * 8;

    const unsigned short* wsW = (const unsigned short*)(ws + WS_W);

    // zero both zbuf buffers once (kk pads stay zero forever)
    {
        uint4* zr = (uint4*)&zbuf[0][0][0];
#pragma unroll
        for (int j = 0; j < 9; ++j) zr[tid + j * 256] = make_uint4(0, 0, 0, 0);
    }

    const float cs = 0.49803922f;   // 127/255

    // ---- block-constant coarse patch base ----
    int cy0 = (int)floorf((float)(ty0 - 3) * cs); cy0 = min(max(cy0, 0), 114);
    int cx0 = (int)floorf((float)(tx0 - 3) * cs); cx0 = min(max(cx0, 0), 114);

    // ---- coarse loader invariants (1 elem/thread, 196 used) ----
    const bool cok = tid < 196;
    const int ci = tid / 14, cj = tid - ci * 14;
    const int cgoff = (cy0 + ci) * W + (cx0 + cj);
    const int cwidx = ci * 15 + cj;
    float cv0 = 0.f, cv1 = 0.f;

    auto cload = [&](int g) {
        if (cok) {
            const float* b = img + ((size_t)n * CIN + 2 * g) * (H * W) + cgoff;
            cv0 = b[0];
            cv1 = b[H * W];
        }
    };
    auto cwrite = [&](int q) {
        if (cok) coarse[q][cwidx] = (f32x2){cv0, cv1};
    };

    // ---- fine-halo metadata: 484 elems, 2 slots, packed u32 + fy + fx ----
    unsigned fM[2];
    float fFY[2], fFX[2];
#pragma unroll
    for (int j = 0; j < 2; ++j) {
        int e = tid + j * 256;
        if (e < 484) {
            int hy = e / 22, hx = e - hy * 22;
            int uy = ty0 - 3 + hy, ux = tx0 - 3 + hx;
            unsigned zf = (((unsigned)uy >= 256u) || ((unsigned)ux >= 256u)) ? 1u : 0u;
            float syf = (float)uy * cs;
            float sxf = (float)ux * cs;
            int y0 = (int)floorf(syf);
            int x0 = (int)floorf(sxf);
            fFY[j] = syf - (float)y0;
            fFX[j] = sxf - (float)x0;
            int y0c = min(max(y0, 0), 127), x0c = min(max(x0, 0), 127);
            int dyo = min(y0c + 1, 127) - y0c;            // 0/1
            int dxo = min(x0c + 1, 127) - x0c;            // 0/1
            unsigned A = (unsigned)((y0c - cy0) * 15 + (x0c - cx0));
            fM[j] = A | ((unsigned)dxo << 9) | ((unsigned)dyo << 10) | (zf << 11)
                      | ((unsigned)(hy * HSX + hx) << 12);
        }
    }

    auto fine_build = [&](int q) {
#pragma unroll
        for (int j = 0; j < 2; ++j)
            if (tid < 484 - j * 256) {
                unsigned m = fM[j];
                const f32x2* cb = &coarse[q][0];
                int A = m & 511;
                int dxo = (m >> 9) & 1;
                int dyo = ((m >> 10) & 1) * 15;
                f32x2 c00 = cb[A],       c01 = cb[A + dxo];
                f32x2 c10 = cb[A + dyo], c11 = cb[A + dyo + dxo];
                f32x2 fyv = (f32x2){fFY[j], fFY[j]};
                f32x2 fxv = (f32x2){fFX[j], fFX[j]};
                f32x2 t0 = c00 + fyv * (c10 - c00);
                f32x2 t1 = c01 + fyv * (c11 - c01);
                f32x2 v  = t0 + fxv * (t1 - t0);
                if (m & (1u << 11)) v = (f32x2){0.f, 0.f};
                halo[q][m >> 12] = v;
            }
    };

    auto zphase = [&](int p) {
        const f32x2* hb = &halo[p][hbase - 72];   // all imm offsets >= 0
        f32x2 z[9];
#pragma unroll
        for (int k = 0; k < 9; ++k) z[k] = (f32x2){0.f, 0.f};
#pragma unroll
        for (int t = 0; t < NT; ++t) {
            f32x2 h = hb[72 + TT.off[t]];
#pragma unroll
            for (int k = 0; k < 9; ++k)
                if (TT.nz[t][k]) z[k] += h * TT.val[t][k];   // v_pk_fma_f32
        }
        unsigned short* zr = &zbuf[p][tid][0];
        ((uint2*)zr)[0] = make_uint2(pkrtz(z[0].x, z[1].x), pkrtz(z[2].x, z[3].x));
        ((uint2*)zr)[1] = make_uint2(pkrtz(z[4].x, z[5].x), pkrtz(z[6].x, z[7].x));
        zr[8] = (unsigned short)(__float_as_uint(z[8].x) >> 16);
        ((uint2*)(zr + 16))[0] = make_uint2(pkrtz(z[0].y, z[1].y), pkrtz(z[2].y, z[3].y));
        ((uint2*)(zr + 16))[1] = make_uint2(pkrtz(z[4].y, z[5].y), pkrtz(z[6].y, z[7].y));
        zr[24] = (unsigned short)(__float_as_uint(z[8].y) >> 16);
    };

    f32x4 acc[4][4];
#pragma unroll
    for (int m = 0; m < 4; ++m)
#pragma unroll
        for (int t = 0; t < 4; ++t) acc[m][t] = (f32x4){0.f, 0.f, 0.f, 0.f};

    // ---- prologue: coarse[0]=pair0, halo[0]=pair0, coarse[1]=pair1, regs=pair2
    cload(0); cwrite(0);
    __syncthreads();
    fine_build(0);        // coarse[0] -> halo[0]
    cload(1);
    __syncthreads();
    cwrite(1);            // regs(pair1) -> coarse[1]
    cload(2);
    __syncthreads();

#pragma unroll 1
    for (int i = 0; i <= 32; ++i) {
        // matrix pipe first: MFMA for pair i-1 (zbuf[(i-1)&1], weights i-1)
        if (i >= 1) {
            const int zp = (i - 1) & 1;
            bf16x8 af[4];
            const unsigned short* wp = wsW + (i - 1) * 2048 + a16 * 32 + kseg;
#pragma unroll
            for (int m = 0; m < 4; ++m)
                af[m] = *(const bf16x8*)(wp + m * 512);
            union { uint2 q2[2]; bf16x8 v; } bfr;
#pragma unroll
            for (int t = 0; t < 4; ++t) {
                const unsigned short* zp2 = &zbuf[zp][wv * 64 + t * 16 + a16][kseg];
                bfr.q2[0] = *(const uint2*)zp2;
                bfr.q2[1] = *(const uint2*)(zp2 + 4);
#pragma unroll
                for (int m = 0; m < 4; ++m)
                    acc[m][t] = __builtin_amdgcn_mfma_f32_16x16x32_bf16(af[m], bfr.v, acc[m][t], 0, 0, 0);
            }
        }
        if (i < 32)  zphase(i & 1);          // halo[i&1] -> zbuf[i&1]   (pair i)
        if (i <= 29) cwrite(i & 1);          // regs(pair i+2) -> coarse[i&1]
        if (i <= 30) fine_build((i + 1) & 1);// coarse[(i+1)&1] -> halo[(i+1)&1]
        if (i <= 28) cload(i + 3);           // global -> regs (pair i+3)
        __syncthreads();
    }

    // ---- epilogue: instance-norm partials + store y ----
#pragma unroll
    for (int m = 0; m < 4; ++m) {
#pragma unroll
        for (int r4 = 0; r4 < 4; ++r4) {
            float s = 0.f, q = 0.f;
#pragma unroll
            for (int t = 0; t < 4; ++t) {
                float v = acc[m][t][r4];
                s += v; q = fmaf(v, v, q);
            }
#pragma unroll
            for (int msk = 1; msk < 16; msk <<= 1) {
                s += __shfl_xor(s, msk);
                q += __shfl_xor(q, msk);
            }
            if (a16 == 0) {
                int o = m * 16 + (l >> 4) * 4 + r4;
                red1[wv][o] = s;
                red2[wv][o] = q;
            }
        }
    }

    const size_t nbase = (size_t)n * COUT * (H2 * W2);
#pragma unroll
    for (int m = 0; m < 4; ++m)
#pragma unroll
        for (int t = 0; t < 4; ++t) {
            int Y = ty0 + wv * 4 + t;
            int X = tx0 + a16;
#pragma unroll
            for (int r4 = 0; r4 < 4; ++r4) {
                int o = m * 16 + (l >> 4) * 4 + r4;
                out[nbase + (size_t)o * (H2 * W2) + Y * W2 + X] = acc[m][t][r4];
            }
        }
    __syncthreads();
    if (tid < 64) {
        float S1 = red1[0][tid] + red1[1][tid] + red1[2][tid] + red1[3][tid];
        float S2 = red2[0][tid] + red2[1][tid] + red2[2][tid] + red2[3][tid];
        ws[WS_P1 + (n * COUT + tid) * 256 + tile] = S1;
        ws[WS_P2 + (n * COUT + tid) * 256 + tile] = S2;
    }
}

// ---------------------------------------------------------------------------
// Stats: reduce 256 tile-partials per (n,c)
// ---------------------------------------------------------------------------
__global__ void stats_kernel(float* __restrict__ ws) {
    const int co  = blockIdx.x;
    const int tid = threadIdx.x;   // 256
    float s1 = ws[WS_P1 + co * 256 + tid];
    float s2 = ws[WS_P2 + co * 256 + tid];
#pragma unroll
    for (int m = 1; m < 64; m <<= 1) { s1 += __shfl_xor(s1, m); s2 += __shfl_xor(s2, m); }
    __shared__ float r1[4], r2[4];
    if ((tid & 63) == 0) { r1[tid >> 6] = s1; r2[tid >> 6] = s2; }
    __syncthreads();
    if (tid == 0) {
        float S1 = r1[0] + r1[1] + r1[2] + r1[3];
        float S2 = r2[0] + r2[1] + r2[2] + r2[3];
        const float inv = 1.f / 65536.f;
        float mu  = S1 * inv;
        float var = S2 * inv - mu * mu;
        ws[WS_MU + co]   = mu;
        ws[WS_RSTD + co] = 1.f / sqrtf(var + 1e-5f);
    }
}

// ---------------------------------------------------------------------------
// Normalize + LeakyReLU(0.2), in place on d_out
// ---------------------------------------------------------------------------
__global__ void norm_kernel(float* __restrict__ out, const float* __restrict__ ws) {
    const int total = NB * COUT * H2 * W2 / 4;
    for (int idx = blockIdx.x * blockDim.x + threadIdx.x; idx < total;
         idx += gridDim.x * blockDim.x) {
        int co = idx >> 14;
        float mu = ws[WS_MU + co];
        float rs = ws[WS_RSTD + co];
        float4 v = ((float4*)out)[idx];
        float* p = (float*)&v;
#pragma unroll
        for (int j = 0; j < 4; ++j) {
            float t = (p[j] - mu) * rs;
            p[j] = (t >= 0.f) ? t : 0.2f * t;
        }
        ((float4*)out)[idx] = v;
    }
}

extern "C" void kernel_launch(void* const* d_in, const int* in_sizes, int n_in,
                              void* d_out, int out_size, void* d_ws, size_t ws_size,
                              hipStream_t stream) {
    const float* img = (const float*)d_in[0];
    const float* wgt = (const float*)d_in[1];
    float* out = (float*)d_out;
    float* ws  = (float*)d_ws;

    setup_w<<<32, 256, 0, stream>>>(wgt, ws);
    conv_kernel<<<NB * 256, 256, 0, stream>>>(img, out, ws);
    stats_kernel<<<256, 256, 0, stream>>>(ws);
    norm_kernel<<<2048, 256, 0, stream>>>(out, ws);
}